// Round 2
// baseline (389.116 us; speedup 1.0000x reference)
//
#include <hip/hip_runtime.h>

typedef unsigned int u32;
typedef unsigned long long u64;

#define R_ROUNDS 64
#define HID 256
#define BATCH 16384
#define RPW 4   // batch rows per wave

// ---------------------------------------------------------------------------
// GF(2) reduction of the reference:
//   s' = (floor(s@M^T + n)) mod 2  with s,n in {0,1}, M in {-1,0,1}
//      = parity(popcount(s & (M!=0) row)) XOR n          (since -1 == 1 mod 2)
//
// pi-order packing: lane l owns bits {4l..4l+3}. Packed u64 word k has
// bit l = vector bit (4l+k). This makes ALL global accesses float4/uint4:
//   noise/state/out: lane l <-> elements 4l..4l+3 (one dwordx4 per row)
//   masks: lane l's 4 output rows = 128 contiguous bytes.
// ---------------------------------------------------------------------------

// Pack ternary matrices -> pi-ordered bitmasks. One wave per (r,j) row.
// Mask word W_i (u64) of row: bit l = (M[row][4l+i] != 0).
// Stored as P[row*8 + 2i+h], h = lo/hi half.  Total 512 KB in d_ws.
__global__ __launch_bounds__(256) void pack_matrices_kernel(
        const float* __restrict__ M, u32* __restrict__ P) {
    const int lane = threadIdx.x & 63;
    const int row  = (int)((blockIdx.x * blockDim.x + threadIdx.x) >> 6); // 0..16383
    const float4 v = *(const float4*)(M + (size_t)row * HID + 4 * lane);
    const u64 b0 = __ballot(v.x != 0.0f);
    const u64 b1 = __ballot(v.y != 0.0f);
    const u64 b2 = __ballot(v.z != 0.0f);
    const u64 b3 = __ballot(v.w != 0.0f);
    if (lane < 8) {
        const int i = lane >> 1;
        u64 bb = b0;                       // cndmask chain, no scratch
        if (i == 1) bb = b1;
        if (i == 2) bb = b2;
        if (i == 3) bb = b3;
        P[row * 8 + lane] = (lane & 1) ? (u32)(bb >> 32) : (u32)bb;
    }
}

__global__ __launch_bounds__(256, 4) void tenshash_kernel(
        const float* __restrict__ state,
        const u32*  __restrict__ pA,
        const float* __restrict__ noise,
        float* __restrict__ out) {
    const int lane = threadIdx.x & 63;
    const int wave = (int)((blockIdx.x * blockDim.x + threadIdx.x) >> 6);
    const int row0 = wave * RPW;

    // ---- init state (pi-order): S_k[rw] bit l = state bit (4l+k) ----
    u64 S0[RPW], S1[RPW], S2[RPW], S3[RPW];
#pragma unroll
    for (int rw = 0; rw < RPW; ++rw) {
        const float4 v = *(const float4*)(state + (size_t)(row0 + rw) * HID + 4 * lane);
        S0[rw] = __ballot(v.x != 0.0f);
        S1[rw] = __ballot(v.y != 0.0f);
        S2[rw] = __ballot(v.z != 0.0f);
        S3[rw] = __ballot(v.w != 0.0f);
    }

    // lane-local bases
    const u32*   pA_l = pA + 32 * lane;                                // rows 4l..4l+3, 128 B
    const float* no_l = noise + (size_t)row0 * (R_ROUNDS * HID) + 4 * lane;

    uint4  aA[8], aB[8];      // double-buffered mask rows (32+32 VGPRs)
    float4 nA[RPW], nB[RPW];  // double-buffered noise     (16+16 VGPRs)

    auto LOAD_A = [&](uint4* a, int r) {
        const uint4* p = (const uint4*)(pA_l + r * (HID * 8));
#pragma unroll
        for (int t = 0; t < 8; ++t) a[t] = p[t];
    };
    auto LOAD_N = [&](float4* n, int r) {
#pragma unroll
        for (int rw = 0; rw < RPW; ++rw)
            n[rw] = *(const float4*)(no_l + (size_t)rw * (R_ROUNDS * HID) + r * HID);
    };
    auto COMPUTE = [&](const uint4* a, const float4* n) {
#pragma unroll
        for (int rw = 0; rw < RPW; ++rw) {
            u64 ns0, ns1, ns2, ns3;
#pragma unroll
            for (int i = 0; i < 4; ++i) {
                // mask u64 words for output bit j = 4l+i (row j = a[2i],a[2i+1])
                const u64 W0 = (u64)a[2 * i].x     | ((u64)a[2 * i].y     << 32);
                const u64 W1 = (u64)a[2 * i].z     | ((u64)a[2 * i].w     << 32);
                const u64 W2 = (u64)a[2 * i + 1].x | ((u64)a[2 * i + 1].y << 32);
                const u64 W3 = (u64)a[2 * i + 1].z | ((u64)a[2 * i + 1].w << 32);
                const float nfv = (i == 0) ? n[rw].x : (i == 1) ? n[rw].y
                                : (i == 2) ? n[rw].z : n[rw].w;
                const u32 c = (u32)__popcll(W0 & S0[rw]) + (u32)__popcll(W1 & S1[rw])
                            + (u32)__popcll(W2 & S2[rw]) + (u32)__popcll(W3 & S3[rw])
                            + (u32)nfv;                       // nfv in {0.0,1.0} exact
                const u64 nb = __ballot((c & 1u) != 0);
                if (i == 0) ns0 = nb; else if (i == 1) ns1 = nb;
                else if (i == 2) ns2 = nb; else ns3 = nb;
            }
            S0[rw] = ns0; S1[rw] = ns1; S2[rw] = ns2; S3[rw] = ns3;
        }
    };

    // ---- software-pipelined 64-round recurrence (depth-1 prefetch) ----
    LOAD_A(aA, 0);
    LOAD_N(nA, 0);
#pragma unroll 1
    for (int r = 0; r < R_ROUNDS; r += 2) {
        LOAD_A(aB, r + 1);                 // r+1 <= 63 always
        LOAD_N(nB, r + 1);
        COMPUTE(aA, nA);                   // round r
        const int r2 = (r + 2 < R_ROUNDS) ? r + 2 : (R_ROUNDS - 1);  // clamped (harmless reload)
        LOAD_A(aA, r2);
        LOAD_N(nA, r2);
        COMPUTE(aB, nB);                   // round r+1
    }

    // ---- unpack final state, float4 stores ----
#pragma unroll
    for (int rw = 0; rw < RPW; ++rw) {
        float4 o;
        o.x = (float)((u32)(S0[rw] >> lane) & 1u);
        o.y = (float)((u32)(S1[rw] >> lane) & 1u);
        o.z = (float)((u32)(S2[rw] >> lane) & 1u);
        o.w = (float)((u32)(S3[rw] >> lane) & 1u);
        *(float4*)(out + (size_t)(row0 + rw) * HID + 4 * lane) = o;
    }
}

extern "C" void kernel_launch(void* const* d_in, const int* in_sizes, int n_in,
                              void* d_out, int out_size, void* d_ws, size_t ws_size,
                              hipStream_t stream) {
    const float* state = (const float*)d_in[0];
    const float* mats  = (const float*)d_in[1];
    const float* noise = (const float*)d_in[2];
    float* out         = (float*)d_out;
    u32* pA            = (u32*)d_ws;              // 512 KB packed masks

    // pack: one wave per matrix row -> 16384 waves
    pack_matrices_kernel<<<(R_ROUNDS * HID) / 4, 256, 0, stream>>>(mats, pA);

    // main: 4096 waves (4 rows each), 1024 blocks
    const int blocks = (BATCH / RPW) / 4;
    tenshash_kernel<<<blocks, 256, 0, stream>>>(state, pA, noise, out);
}

// Round 3
// 230.555 us; speedup vs baseline: 1.6877x; 1.6877x over previous
//
#include <hip/hip_runtime.h>

typedef unsigned int u32;
typedef unsigned long long u64;

#define R_ROUNDS 64
#define HID 256
#define BATCH 16384
#define RPW 4   // batch rows per wave

// ---------------------------------------------------------------------------
// GF(2) reduction of the reference:
//   s' = (floor(s@M^T + n)) mod 2, s,n in {0,1}, M in {-1,0,1}
//      = parity(popcount(s & (M!=0) row)) XOR n        (-1 == 1 mod 2)
//
// pi-order packing: lane l owns bits {4l..4l+3}; packed u64 word k has
// bit l = vector bit (4l+k). All float traffic is dwordx4-coalesced.
// Masks live in LDS (8KB/round, double-buffered), staged via
// global_load_lds with a source-side XOR swizzle so the swizzled
// ds_read_b128 is 2-way-conflict-free (linear LDS dest, rule #21).
// ---------------------------------------------------------------------------

// Pack ternary matrices -> pi-ordered bitmasks. One wave per (r,j) row.
// P[row*8 + 2i+h] = half h of u64 W_i, where W_i bit l = (M[row][4l+i]!=0).
__global__ __launch_bounds__(256) void pack_matrices_kernel(
        const float* __restrict__ M, u32* __restrict__ P) {
    const int lane = threadIdx.x & 63;
    const int row  = (int)((blockIdx.x * blockDim.x + threadIdx.x) >> 6);
    const float4 v = *(const float4*)(M + (size_t)row * HID + 4 * lane);
    const u64 b0 = __ballot(v.x != 0.0f);
    const u64 b1 = __ballot(v.y != 0.0f);
    const u64 b2 = __ballot(v.z != 0.0f);
    const u64 b3 = __ballot(v.w != 0.0f);
    if (lane < 8) {
        const int i = lane >> 1;
        u64 bb = b0;
        if (i == 1) bb = b1;
        if (i == 2) bb = b2;
        if (i == 3) bb = b3;
        P[row * 8 + lane] = (lane & 1) ? (u32)(bb >> 32) : (u32)bb;
    }
}

__global__ __launch_bounds__(256, 4) void tenshash_kernel(
        const float* __restrict__ state,
        const u32*  __restrict__ pA,
        const float* __restrict__ noise,
        float* __restrict__ out) {
    const int lane = threadIdx.x & 63;
    const int warp = threadIdx.x >> 6;
    const int wave = (int)(blockIdx.x * 4 + warp);
    const int row0 = wave * RPW;

    __shared__ u32 smem[2][2048];   // 2 x 8KB mask double-buffer

    // ---- init state (pi-order): S_k[rw] bit l = state bit (4l+k) ----
    u64 S0[RPW], S1[RPW], S2[RPW], S3[RPW];
#pragma unroll
    for (int rw = 0; rw < RPW; ++rw) {
        const float4 v = *(const float4*)(state + (size_t)(row0 + rw) * HID + 4 * lane);
        S0[rw] = __ballot(v.x != 0.0f);
        S1[rw] = __ballot(v.y != 0.0f);
        S2[rw] = __ballot(v.z != 0.0f);
        S3[rw] = __ballot(v.w != 0.0f);
    }

    const float* no_l = noise + (size_t)row0 * (R_ROUNDS * HID) + 4 * lane;

    // Source-side swizzle for staging: LDS 16B-slot u' = 64*t + lane must
    // hold global 16B-chunk f(u') = u' ^ ((u'>>3)&7) = 64t + 8a + (b^a),
    // a = lane>>3, b = lane&7. (Inverse of the read swizzle below.)
    const int sa = lane >> 3, sb = lane & 7;
    const int src_chunk_lo = (sa << 3) + (sb ^ sa);           // within-1KB chunk
    // Staging: wave 0 issues 8 x global_load_lds(16B) = 8KB round block.
    auto STAGE = [&](int r, int b) {
        if (warp == 0) {
            const char* g = (const char*)(pA + (size_t)r * 2048);
#pragma unroll
            for (int t = 0; t < 8; ++t) {
                __builtin_amdgcn_global_load_lds(
                    (const __attribute__((address_space(1))) void*)
                        (g + t * 1024 + src_chunk_lo * 16),
                    (__attribute__((address_space(3))) void*)&smem[b][t * 256],
                    16, 0, 0);
            }
        }
    };
    auto LOADN = [&](float4* n, int r) {
#pragma unroll
        for (int rw = 0; rw < RPW; ++rw)
            n[rw] = *(const float4*)(no_l + (size_t)rw * (R_ROUNDS * HID) + r * HID);
    };
    // Swizzled LDS read: a[t] = chunk (8*lane + t) read from slot
    // 8*lane + (t ^ (lane&7))  -> banks spread, 2-way only (free).
    auto RUN = [&](int b, const float4* n) {
        const uint4* p = (const uint4*)&smem[b][0];
        uint4 a[8];
#pragma unroll
        for (int t = 0; t < 8; ++t)
            a[t] = p[(lane << 3) + (t ^ (lane & 7))];
#pragma unroll
        for (int rw = 0; rw < RPW; ++rw) {
            u64 ns0, ns1, ns2, ns3;
#pragma unroll
            for (int i = 0; i < 4; ++i) {
                const u64 W0 = (u64)a[2 * i].x     | ((u64)a[2 * i].y     << 32);
                const u64 W1 = (u64)a[2 * i].z     | ((u64)a[2 * i].w     << 32);
                const u64 W2 = (u64)a[2 * i + 1].x | ((u64)a[2 * i + 1].y << 32);
                const u64 W3 = (u64)a[2 * i + 1].z | ((u64)a[2 * i + 1].w << 32);
                const float nfv = (i == 0) ? n[rw].x : (i == 1) ? n[rw].y
                                : (i == 2) ? n[rw].z : n[rw].w;
                const u32 c = (u32)__popcll(W0 & S0[rw]) + (u32)__popcll(W1 & S1[rw])
                            + (u32)__popcll(W2 & S2[rw]) + (u32)__popcll(W3 & S3[rw])
                            + (u32)nfv;                    // exact: nfv in {0.0,1.0}
                const u64 nb = __ballot((c & 1u) != 0);
                if (i == 0) ns0 = nb; else if (i == 1) ns1 = nb;
                else if (i == 2) ns2 = nb; else ns3 = nb;
            }
            S0[rw] = ns0; S1[rw] = ns1; S2[rw] = ns2; S3[rw] = ns3;
        }
    };

    // ---- pipelined rounds: stage/noise r+1 in flight under compute r ----
    float4 nA[RPW], nB[RPW];
    STAGE(0, 0);
    LOADN(nA, 0);
    __syncthreads();                      // drains stage(0) + noise(0)
#pragma unroll 1
    for (int r = 0; r < R_ROUNDS; r += 2) {
        STAGE(r + 1, 1);                  // r+1 <= 63 always
        LOADN(nB, r + 1);
        RUN(0, nA);                       // round r
        __syncthreads();                  // buf1 + nB ready
        if (r + 2 < R_ROUNDS) {
            STAGE(r + 2, 0);
            LOADN(nA, r + 2);
        }
        RUN(1, nB);                       // round r+1
        __syncthreads();                  // buf0 + nA ready
    }

    // ---- unpack final state, float4 stores ----
#pragma unroll
    for (int rw = 0; rw < RPW; ++rw) {
        float4 o;
        o.x = (float)((u32)(S0[rw] >> lane) & 1u);
        o.y = (float)((u32)(S1[rw] >> lane) & 1u);
        o.z = (float)((u32)(S2[rw] >> lane) & 1u);
        o.w = (float)((u32)(S3[rw] >> lane) & 1u);
        *(float4*)(out + (size_t)(row0 + rw) * HID + 4 * lane) = o;
    }
}

extern "C" void kernel_launch(void* const* d_in, const int* in_sizes, int n_in,
                              void* d_out, int out_size, void* d_ws, size_t ws_size,
                              hipStream_t stream) {
    const float* state = (const float*)d_in[0];
    const float* mats  = (const float*)d_in[1];
    const float* noise = (const float*)d_in[2];
    float* out         = (float*)d_out;
    u32* pA            = (u32*)d_ws;              // 512 KB packed masks

    pack_matrices_kernel<<<(R_ROUNDS * HID) / 4, 256, 0, stream>>>(mats, pA);

    const int blocks = (BATCH / RPW) / 4;         // 1024 blocks x 4 waves
    tenshash_kernel<<<blocks, 256, 0, stream>>>(state, pA, noise, out);
}